// Round 10
// baseline (884.992 us; speedup 1.0000x reference)
//
#include <hip/hip_runtime.h>

typedef __attribute__((ext_vector_type(8))) short bf16x8;
typedef __attribute__((ext_vector_type(4))) float f32x4;

#define NEG_SLOPE 0.2f

__device__ __forceinline__ unsigned short f2bf(float f){
  unsigned u = __float_as_uint(f);
  u = (u + 0x7fffu + ((u >> 16) & 1u)) >> 16;   // RNE
  return (unsigned short)u;
}
__device__ __forceinline__ float bflo(unsigned u){ return __uint_as_float(u << 16); }
__device__ __forceinline__ float bfhi(unsigned u){ return __uint_as_float(u & 0xffff0000u); }

// ---------------------------------------------------------------------------
// K1: fused [hist | type-hist | bprep].
// Blocks [0,nbHist): histogram both segment spaces (edge + vertex).
// Blocks [nbHist, nbHist+nbHN): histogram node types into tcnt[4].
// Blocks [nbHist+nbHN, +256): pack W_typed fp32 -> bf16 MFMA B-frag order.
// ---------------------------------------------------------------------------
__global__ __launch_bounds__(256) void k_histprep(
    const int* __restrict__ edges, const int* __restrict__ vertex, int NNZ,
    int* __restrict__ cnt, int E, int nbHist,
    const int* __restrict__ vtype, int N, int* __restrict__ tcnt, int nbHN,
    const float* __restrict__ W, short* __restrict__ Bfrag){
  int b = (int)blockIdx.x;
  if (b < nbHist){
    int i = b * 256 + threadIdx.x;
    if (i < NNZ){
      atomicAdd(cnt + edges[i], 1);
      atomicAdd(cnt + E + vertex[i], 1);
    }
    return;
  }
  b -= nbHist;
  if (b < nbHN){
    int i = b * 256 + threadIdx.x;
    if (i < N) atomicAdd(tcnt + vtype[i], 1);
    return;
  }
  b -= nbHN;
  int u = b * 256 + threadIdx.x;                   // 0..65535
  int j = u & 7, lane = (u >> 3) & 63, ct = (u >> 9) & 31, ks = u >> 14;
  int k = ks * 32 + ((lane >> 4) << 3) + j;
  int col = (ct << 4) + (lane & 15);
  int t = col >> 7, o = col & 127;
  Bfrag[u] = (short)f2bf(W[(t * 128 + k) * 128 + o]);
}

// ---------------------------------------------------------------------------
// Prefix scan over cnt -> offs (+cursor copy); scanB also derives padded
// type-bucket bases pbase[5] (64-row multiples) from tcnt.
// ---------------------------------------------------------------------------
__global__ __launch_bounds__(256) void k_scanA(const int* __restrict__ cnt, int S,
                                               int* __restrict__ bsum){
  __shared__ int sh[256];
  int base = blockIdx.x * 1024 + threadIdx.x * 4;
  int s = 0;
  #pragma unroll
  for (int k = 0; k < 4; ++k){ int idx = base + k; if (idx < S) s += cnt[idx]; }
  sh[threadIdx.x] = s; __syncthreads();
  for (int off = 128; off > 0; off >>= 1){
    if (threadIdx.x < off) sh[threadIdx.x] += sh[threadIdx.x + off];
    __syncthreads();
  }
  if (threadIdx.x == 0) bsum[blockIdx.x] = sh[0];
}

__global__ void k_scanB(int* bsum, int nb, const int* __restrict__ tcnt,
                        int* __restrict__ pbase){
  if (threadIdx.x == 0 && blockIdx.x == 0){
    int run = 0;
    for (int b = 0; b < nb; ++b){ int v = bsum[b]; bsum[b] = run; run += v; }
    int pb = 0;
    for (int t = 0; t < 4; ++t){
      pbase[t] = pb;
      pb += ((tcnt[t] + 63) >> 6) << 6;            // pad to 64-row multiple
    }
    pbase[4] = pb;
  }
}

// ---------------------------------------------------------------------------
// scanC (+fused node-placement). Blocks [0,nbS): big scan -> offs/cursor.
// Blocks [nbS, nbS+nbHN): place nodes type-sorted into nsorted (block-local
// LDS ranking -> 4 global atomics per block).
// ---------------------------------------------------------------------------
__global__ __launch_bounds__(256) void k_scanC(const int* __restrict__ cnt, int S,
    const int* __restrict__ bsum, int* __restrict__ offs, int* __restrict__ cursor,
    int nbS, const int* __restrict__ vtype, int N, const int* __restrict__ pbase,
    int* __restrict__ tcur, int* __restrict__ nsorted){
  __shared__ int sh[256];
  __shared__ int gbase[4];
  int t = threadIdx.x;
  int b = (int)blockIdx.x;
  if (b >= nbS){                                   // node-place role
    int* lcnt = sh;
    if (t < 4) lcnt[t] = 0;
    __syncthreads();
    int i = (b - nbS) * 256 + t;
    int tt = 0, rank = 0;
    bool valid = i < N;
    if (valid){ tt = vtype[i]; rank = atomicAdd(&lcnt[tt], 1); }
    __syncthreads();
    if (t < 4 && lcnt[t] > 0) gbase[t] = atomicAdd(tcur + t, lcnt[t]);
    __syncthreads();
    if (valid) nsorted[pbase[tt] + gbase[tt] + rank] = i;
    return;
  }
  int base = b * 1024 + t * 4;
  int c[4]; int s = 0;
  #pragma unroll
  for (int k = 0; k < 4; ++k){ int idx = base + k; c[k] = (idx < S) ? cnt[idx] : 0; s += c[k]; }
  sh[t] = s; __syncthreads();
  for (int off = 1; off < 256; off <<= 1){
    int v = (t >= off) ? sh[t - off] : 0; __syncthreads();
    sh[t] += v; __syncthreads();
  }
  int run = bsum[b] + sh[t] - s;                   // exclusive prefix for this thread
  #pragma unroll
  for (int k = 0; k < 4; ++k){
    int idx = base + k;
    if (idx < S){ offs[idx] = run; cursor[idx] = run; run += c[k]; }
  }
}

// ---------------------------------------------------------------------------
// F_A: fused [type-sorted gemm | place_e], MODULO-interleaved period 3
// (role 0 = gemm, roles 1,2 = place_e).
// gemm: block q handles 64 same-type rows nsorted[q*64 .. +64) (buckets are
// padded to 64-multiples; sentinel rows = -1; nsorted is sized AND memset to
// the full grid coverage nbPad*64 — R9 crash was an OOB read past N+256).
// Only the block's type B-slab (128 cols x 128 K = 32KB bf16) is staged —
// acc is 8 tiles (32 VGPR), MFMA/ds_read work 1/4 of the all-type version.
// K-accumulation order (ks ascending per ct) identical to R8 -> bit-identical.
// ---------------------------------------------------------------------------
__global__ __launch_bounds__(256, 3) void k_gemm_place(const float* __restrict__ X,
    const short* __restrict__ Bfrag, const int* __restrict__ nsorted,
    const int* __restrict__ pbase, unsigned short* __restrict__ X0,
    const int* __restrict__ edges, const int* __restrict__ vertex, int NNZ,
    int* __restrict__ cursor, int* __restrict__ rows, int nbPlace){
  __shared__ short shB[8 * 4 * 64 * 8];            // 32KB: type slab, frag order
  const int tid = threadIdx.x;
  const int q = (int)blockIdx.x / 3, r = (int)blockIdx.x % 3;

  if (r != 0){                                     // place_e role
    int hb = 2 * q + (r - 1);
    if (hb < nbPlace){
      int i = hb * 256 + tid;
      if (i < NNZ){
        int pos = atomicAdd(cursor + edges[i], 1);
        rows[pos] = vertex[i];
      }
    }
    return;
  }

  const int rowIdx = q * 64;
  const int t = (rowIdx >= pbase[1]) + (rowIdx >= pbase[2]) + (rowIdx >= pbase[3]);

  // stage this type's full B (8 ct x 4 ks x 64 lanes, bf16x8 units)
  const bf16x8* Bv = (const bf16x8*)Bfrag;
  bf16x8* shBv = (bf16x8*)shB;
  #pragma unroll
  for (int v = 0; v < 8; ++v){
    int item = v * 256 + tid;                      // 0..2047
    int slab = item >> 6, ln = item & 63;          // slab = ks*8 + ctl
    int ks = slab >> 3, ctl = slab & 7;
    shBv[item] = Bv[((ks * 32 + 8 * t + ctl) * 64) + ln];
  }

  const int w = tid >> 6, lane = tid & 63;
  const int m = lane & 15, qq = lane >> 4;
  const int node = nsorted[rowIdx + w * 16 + m];   // -1 = pad sentinel

  bf16x8 afrag[4];
  #pragma unroll
  for (int ks = 0; ks < 4; ++ks){
    bf16x8 f;
    if (node >= 0){
      const float4* src = (const float4*)(X + (size_t)node * 128 + ks * 32 + qq * 8);
      float4 a = src[0], b = src[1];
      f[0]=(short)f2bf(a.x); f[1]=(short)f2bf(a.y); f[2]=(short)f2bf(a.z); f[3]=(short)f2bf(a.w);
      f[4]=(short)f2bf(b.x); f[5]=(short)f2bf(b.y); f[6]=(short)f2bf(b.z); f[7]=(short)f2bf(b.w);
    } else {
      #pragma unroll
      for (int z = 0; z < 8; ++z) f[z] = 0;
    }
    afrag[ks] = f;
  }

  f32x4 acc[8];
  #pragma unroll
  for (int ct = 0; ct < 8; ++ct){
    acc[ct][0]=0.f; acc[ct][1]=0.f; acc[ct][2]=0.f; acc[ct][3]=0.f;
  }

  __syncthreads();
  #pragma unroll
  for (int ctl = 0; ctl < 8; ++ctl){
    #pragma unroll
    for (int ks = 0; ks < 4; ++ks){
      bf16x8 bf = shBv[(ks * 8 + ctl) * 64 + lane];
      acc[ctl] = __builtin_amdgcn_mfma_f32_16x16x32_bf16(afrag[ks], bf, acc[ctl], 0, 0, 0);
    }
  }

  const int col0 = lane & 15;
  #pragma unroll
  for (int rr = 0; rr < 4; ++rr){
    int row = nsorted[rowIdx + w * 16 + qq * 4 + rr];
    if (row < 0) continue;
    #pragma unroll
    for (int ctl = 0; ctl < 8; ++ctl)
      X0[(size_t)row * 128 + ctl * 16 + col0] = f2bf(acc[ctl][rr]);
  }
}

// ---------------------------------------------------------------------------
// seg_body v1-ILP2 (R8-proven): 2 rows/iter, independent shfl-reduce chains.
// Lane l owns output elems [2l, 2l+1]; head h = l>>3. offs/cnt hold GLOBAL
// positions into the unified rows buffer — pass BASE rows.
// ---------------------------------------------------------------------------
template<int OUT_BF16, int DO_RELU>
__device__ __forceinline__ void seg_body(const unsigned* __restrict__ feat,
    const float* __restrict__ att, const int* __restrict__ rows_sorted,
    const int* __restrict__ offs, const int* __restrict__ cnt,
    const int* __restrict__ stype, void* __restrict__ outbuf,
    int S, int blockId, int tid){
  int wid = tid >> 6, lane = tid & 63;
  int s = blockId * 4 + wid;
  if (s >= S) return;
  int t = stype[s];
  float a0 = att[t * 128 + 2 * lane], a1 = att[t * 128 + 2 * lane + 1];
  int start = offs[s], len = cnt[s];
  float denom = 0.f, acc0 = 0.f, acc1 = 0.f;

  for (int base = 0; base < len; base += 64){
    int m = len - base; if (m > 64) m = 64;
    int idx = 0;
    if (lane < m) idx = rows_sorted[start + base + lane];

    unsigned u0 = 0, u1 = 0, u2 = 0, u3 = 0;
    {
      int r;
      r = __shfl(idx, 0); if (0 < m) u0 = feat[(size_t)r * 64 + lane];
      r = __shfl(idx, 1); if (1 < m) u1 = feat[(size_t)r * 64 + lane];
      r = __shfl(idx, 2); if (2 < m) u2 = feat[(size_t)r * 64 + lane];
      r = __shfl(idx, 3); if (3 < m) u3 = feat[(size_t)r * 64 + lane];
    }
    for (int j = 0; j < m; j += 2){
      unsigned ua = u0, ub = u1;
      u0 = u2; u1 = u3;
      if (j + 4 < m){ int rn = __shfl(idx, j + 4); u2 = feat[(size_t)rn * 64 + lane]; }
      if (j + 5 < m){ int rn = __shfl(idx, j + 5); u3 = feat[(size_t)rn * 64 + lane]; }

      float xa0 = bflo(ua), xa1 = bfhi(ua);
      float xb0 = bflo(ub), xb1 = bfhi(ub);
      float pa = xa0 * a0 + xa1 * a1;
      float pb = xb0 * a0 + xb1 * a1;
      pa += __shfl_xor(pa, 1);  pb += __shfl_xor(pb, 1);
      pa += __shfl_xor(pa, 2);  pb += __shfl_xor(pb, 2);
      pa += __shfl_xor(pa, 4);  pb += __shfl_xor(pb, 4);
      pa = pa > 0.f ? pa : NEG_SLOPE * pa;
      float wa = __expf(pa);
      denom += wa; acc0 += wa * xa0; acc1 += wa * xa1;
      if (j + 1 < m){
        pb = pb > 0.f ? pb : NEG_SLOPE * pb;
        float wb = __expf(pb);
        denom += wb; acc0 += wb * xb0; acc1 += wb * xb1;
      }
    }
  }
  float inv = 1.f / (denom + 1e-16f);
  float v0 = acc0 * inv, v1 = acc1 * inv;
  if (DO_RELU){ v0 = fmaxf(v0, 0.f); v1 = fmaxf(v1, 0.f); }
  if (OUT_BF16){
    unsigned pw = (unsigned)f2bf(v0) | ((unsigned)f2bf(v1) << 16);
    ((unsigned*)outbuf)[(size_t)s * 64 + lane] = pw;
  } else {
    ((float2*)outbuf)[(size_t)s * 64 + lane] = make_float2(v0, v1);
  }
}

// ---------------------------------------------------------------------------
// F_B: fused [place_v | seg1], MODULO-interleaved period 5 (role 0 = place,
// roles 1-4 = seg).  place_v writes rows[NNZ,2NNZ); seg1 reads rows[0,NNZ).
// ---------------------------------------------------------------------------
__global__ __launch_bounds__(256) void k_place_seg1(
    const int* __restrict__ edges, const int* __restrict__ vertex, int NNZ,
    int* __restrict__ cursor, int* __restrict__ rows, int E,
    int nbPlace, int nbSeg,
    const unsigned* __restrict__ X0, const float* __restrict__ att_e,
    const int* __restrict__ offs, const int* __restrict__ cnt,
    const int* __restrict__ etype, void* __restrict__ Xe){
  const int q = (int)blockIdx.x / 5, r = (int)blockIdx.x % 5;
  if (r == 0){
    if (q < nbPlace){
      int i = q * 256 + threadIdx.x;
      if (i < NNZ){
        int pos = atomicAdd(cursor + E + vertex[i], 1);
        rows[pos] = edges[i];
      }
    }
    return;
  }
  int segBlk = q * 4 + (r - 1);
  if (segBlk >= nbSeg) return;
  seg_body<1, 1>(X0, att_e, rows, offs, cnt, etype, Xe, E, segBlk, threadIdx.x);
}

__global__ __launch_bounds__(256) void k_seg2(const unsigned* __restrict__ Xe,
    const float* __restrict__ att_v, const int* __restrict__ rows,
    const int* __restrict__ offs, const int* __restrict__ cnt,
    const int* __restrict__ vtype, float* __restrict__ out, int N){
  seg_body<0, 0>(Xe, att_v, rows, offs, cnt, vtype, out, N,
                 (int)blockIdx.x, threadIdx.x);
}

extern "C" void kernel_launch(void* const* d_in, const int* in_sizes, int n_in,
                              void* d_out, int out_size, void* d_ws, size_t ws_size,
                              hipStream_t stream){
  const float* X      = (const float*)d_in[0];
  const float* W      = (const float*)d_in[1];
  const float* att_e  = (const float*)d_in[2];
  const float* att_v  = (const float*)d_in[3];
  const int*   vertex = (const int*)d_in[4];
  const int*   edges  = (const int*)d_in[5];
  const int*   vtype  = (const int*)d_in[6];
  const int*   etype  = (const int*)d_in[7];
  float* out = (float*)d_out;
  const int N   = in_sizes[0] / 128;
  const int NNZ = in_sizes[4];
  const int E   = in_sizes[7];
  const int S   = E + N;

  const int nbI = (NNZ + 255) / 256;                  // 3125 hist/place blocks
  const int nbHN = (N + 255) / 256;                   // 391 type-hist blocks
  const int nbS = (S + 1023) / 1024;
  const int nbSeg1 = (E + 3) / 4;                     // 12500 seg1 blocks
  const int nbPad = (N + 252 + 63) / 64;              // padded gemm blocks
  const int nsortedCap = nbPad * 64;                  // FULL gemm-grid coverage

  // workspace carve
  char* wp = (char*)d_ws;
  int* cnt    = (int*)wp; wp += (size_t)S * 4;        // [0,E) edge, [E,S) vertex
  int* tcnt   = (int*)wp; wp += 16;                   // node-type counts
  int* tcur   = (int*)wp; wp += 16;                   // node-type cursors
  int* offs   = (int*)wp; wp += (size_t)S * 4;
  int* cursor = (int*)wp; wp += (size_t)S * 4;
  int* bsum   = (int*)wp; wp += 1024;                 // up to 256 block sums
  int* pbase  = (int*)wp; wp += 32;                   // padded bucket bases[5]
  int* rows   = (int*)wp; wp += (size_t)2 * NNZ * 4;  // [0,NNZ) edge-grp, [NNZ,2NNZ) vtx-grp
  int* nsorted= (int*)wp; wp += (size_t)nsortedCap * 4; // type-sorted node ids (pad = -1)
  unsigned short* X0 = (unsigned short*)wp; wp += (size_t)N * 128 * 2;
  unsigned short* Xe = (unsigned short*)wp; wp += (size_t)E * 128 * 2;
  short* Bfrag = (short*)wp; wp += (size_t)65536 * 2;

  hipMemsetAsync(cnt, 0, (size_t)(S + 8) * 4, stream);          // cnt + tcnt + tcur
  hipMemsetAsync(nsorted, 0xFF, (size_t)nsortedCap * 4, stream); // -1 sentinels

  k_histprep<<<nbI + nbHN + 256, 256, 0, stream>>>(edges, vertex, NNZ, cnt, E,
      nbI, vtype, N, tcnt, nbHN, W, Bfrag);

  k_scanA<<<nbS, 256, 0, stream>>>(cnt, S, bsum);
  k_scanB<<<1, 64, 0, stream>>>(bsum, nbS, tcnt, pbase);
  k_scanC<<<nbS + nbHN, 256, 0, stream>>>(cnt, S, bsum, offs, cursor,
      nbS, vtype, N, pbase, tcur, nsorted);

  // F_A interleaved: period 3 (1 gemm : 2 place_e); 2*nbPad >= nbI coverage
  k_gemm_place<<<3 * nbPad, 256, 0, stream>>>(X, Bfrag, nsorted, pbase,
      (unsigned short*)X0, edges, vertex, NNZ, cursor, rows, nbI);

  // F_B interleaved: period 5 (1 place_v : 4 seg1); 5*nbI = nbI + nbSeg1
  k_place_seg1<<<5 * nbI, 256, 0, stream>>>(edges, vertex, NNZ, cursor,
      rows, E, nbI, nbSeg1, (const unsigned*)X0, att_e, offs, cnt, etype, Xe);

  // base rows pointer — offs[E..S) are global positions in [NNZ, 2NNZ)
  k_seg2<<<(N + 3) / 4, 256, 0, stream>>>((const unsigned*)Xe, att_v,
      rows, offs + E, cnt + E, vtype, out, N);
}

// Round 11
// 363.494 us; speedup vs baseline: 2.4347x; 2.4347x over previous
//
#include <hip/hip_runtime.h>

typedef __attribute__((ext_vector_type(8))) short bf16x8;
typedef __attribute__((ext_vector_type(4))) float f32x4;

#define NEG_SLOPE 0.2f

__device__ __forceinline__ unsigned short f2bf(float f){
  unsigned u = __float_as_uint(f);
  u = (u + 0x7fffu + ((u >> 16) & 1u)) >> 16;   // RNE
  return (unsigned short)u;
}
__device__ __forceinline__ float bflo(unsigned u){ return __uint_as_float(u << 16); }
__device__ __forceinline__ float bfhi(unsigned u){ return __uint_as_float(u & 0xffff0000u); }

// ---------------------------------------------------------------------------
// K1: fused [hist | type-hist | bprep].
// Blocks [0,nbHist): histogram both segment spaces (edge + vertex).
// Blocks [nbHist, nbHist+nbHN): node-type histogram, LDS-PRIVATIZED —
//   R10 lesson: direct atomicAdd(tcnt+vtype[i]) = 100k RMWs on one cache
//   line = 578 us. Block-local LDS counts then 4 global atomics/block.
// Blocks [nbHist+nbHN, +256): pack W_typed fp32 -> bf16 MFMA B-frag order.
// ---------------------------------------------------------------------------
__global__ __launch_bounds__(256) void k_histprep(
    const int* __restrict__ edges, const int* __restrict__ vertex, int NNZ,
    int* __restrict__ cnt, int E, int nbHist,
    const int* __restrict__ vtype, int N, int* __restrict__ tcnt, int nbHN,
    const float* __restrict__ W, short* __restrict__ Bfrag){
  __shared__ int lcnt[4];
  int b = (int)blockIdx.x;
  if (b < nbHist){
    int i = b * 256 + threadIdx.x;
    if (i < NNZ){
      atomicAdd(cnt + edges[i], 1);
      atomicAdd(cnt + E + vertex[i], 1);
    }
    return;
  }
  b -= nbHist;
  if (b < nbHN){
    if (threadIdx.x < 4) lcnt[threadIdx.x] = 0;
    __syncthreads();
    int i = b * 256 + threadIdx.x;
    if (i < N) atomicAdd(&lcnt[vtype[i]], 1);
    __syncthreads();
    if (threadIdx.x < 4 && lcnt[threadIdx.x] > 0)
      atomicAdd(tcnt + threadIdx.x, lcnt[threadIdx.x]);
    return;
  }
  b -= nbHN;
  int u = b * 256 + threadIdx.x;                   // 0..65535
  int j = u & 7, lane = (u >> 3) & 63, ct = (u >> 9) & 31, ks = u >> 14;
  int k = ks * 32 + ((lane >> 4) << 3) + j;
  int col = (ct << 4) + (lane & 15);
  int t = col >> 7, o = col & 127;
  Bfrag[u] = (short)f2bf(W[(t * 128 + k) * 128 + o]);
}

// ---------------------------------------------------------------------------
// Prefix scan over cnt -> offs (+cursor copy); scanB also derives padded
// type-bucket bases pbase[5] (64-row multiples) from tcnt.
// ---------------------------------------------------------------------------
__global__ __launch_bounds__(256) void k_scanA(const int* __restrict__ cnt, int S,
                                               int* __restrict__ bsum){
  __shared__ int sh[256];
  int base = blockIdx.x * 1024 + threadIdx.x * 4;
  int s = 0;
  #pragma unroll
  for (int k = 0; k < 4; ++k){ int idx = base + k; if (idx < S) s += cnt[idx]; }
  sh[threadIdx.x] = s; __syncthreads();
  for (int off = 128; off > 0; off >>= 1){
    if (threadIdx.x < off) sh[threadIdx.x] += sh[threadIdx.x + off];
    __syncthreads();
  }
  if (threadIdx.x == 0) bsum[blockIdx.x] = sh[0];
}

__global__ void k_scanB(int* bsum, int nb, const int* __restrict__ tcnt,
                        int* __restrict__ pbase){
  if (threadIdx.x == 0 && blockIdx.x == 0){
    int run = 0;
    for (int b = 0; b < nb; ++b){ int v = bsum[b]; bsum[b] = run; run += v; }
    int pb = 0;
    for (int t = 0; t < 4; ++t){
      pbase[t] = pb;
      pb += ((tcnt[t] + 63) >> 6) << 6;            // pad to 64-row multiple
    }
    pbase[4] = pb;
  }
}

// ---------------------------------------------------------------------------
// scanC (+fused node-placement). Blocks [0,nbS): big scan -> offs/cursor.
// Blocks [nbS, nbS+nbHN): place nodes type-sorted into nsorted (block-local
// LDS ranking -> 4 global atomics per block).
// ---------------------------------------------------------------------------
__global__ __launch_bounds__(256) void k_scanC(const int* __restrict__ cnt, int S,
    const int* __restrict__ bsum, int* __restrict__ offs, int* __restrict__ cursor,
    int nbS, const int* __restrict__ vtype, int N, const int* __restrict__ pbase,
    int* __restrict__ tcur, int* __restrict__ nsorted){
  __shared__ int sh[256];
  __shared__ int gbase[4];
  int t = threadIdx.x;
  int b = (int)blockIdx.x;
  if (b >= nbS){                                   // node-place role
    int* lcnt = sh;
    if (t < 4) lcnt[t] = 0;
    __syncthreads();
    int i = (b - nbS) * 256 + t;
    int tt = 0, rank = 0;
    bool valid = i < N;
    if (valid){ tt = vtype[i]; rank = atomicAdd(&lcnt[tt], 1); }
    __syncthreads();
    if (t < 4 && lcnt[t] > 0) gbase[t] = atomicAdd(tcur + t, lcnt[t]);
    __syncthreads();
    if (valid) nsorted[pbase[tt] + gbase[tt] + rank] = i;
    return;
  }
  int base = b * 1024 + t * 4;
  int c[4]; int s = 0;
  #pragma unroll
  for (int k = 0; k < 4; ++k){ int idx = base + k; c[k] = (idx < S) ? cnt[idx] : 0; s += c[k]; }
  sh[t] = s; __syncthreads();
  for (int off = 1; off < 256; off <<= 1){
    int v = (t >= off) ? sh[t - off] : 0; __syncthreads();
    sh[t] += v; __syncthreads();
  }
  int run = bsum[b] + sh[t] - s;                   // exclusive prefix for this thread
  #pragma unroll
  for (int k = 0; k < 4; ++k){
    int idx = base + k;
    if (idx < S){ offs[idx] = run; cursor[idx] = run; run += c[k]; }
  }
}

// ---------------------------------------------------------------------------
// F_A: fused [type-sorted gemm | place_e], MODULO-interleaved period 3
// (role 0 = gemm, roles 1,2 = place_e).
// gemm: block q handles 64 same-type rows nsorted[q*64 .. +64) (buckets are
// padded to 64-multiples; sentinel rows = -1; nsorted sized+memset to full
// grid coverage nbPad*64 — R9 crash was an OOB read past N+256).
// Only the block's type B-slab (128 cols x 128 K = 32KB bf16) is staged —
// acc is 8 tiles (32 VGPR), MFMA/ds_read work 1/4 of the all-type version.
// K-accumulation order (ks ascending per ct) identical to R8 -> bit-identical.
// ---------------------------------------------------------------------------
__global__ __launch_bounds__(256, 3) void k_gemm_place(const float* __restrict__ X,
    const short* __restrict__ Bfrag, const int* __restrict__ nsorted,
    const int* __restrict__ pbase, unsigned short* __restrict__ X0,
    const int* __restrict__ edges, const int* __restrict__ vertex, int NNZ,
    int* __restrict__ cursor, int* __restrict__ rows, int nbPlace){
  __shared__ short shB[8 * 4 * 64 * 8];            // 32KB: type slab, frag order
  const int tid = threadIdx.x;
  const int q = (int)blockIdx.x / 3, r = (int)blockIdx.x % 3;

  if (r != 0){                                     // place_e role
    int hb = 2 * q + (r - 1);
    if (hb < nbPlace){
      int i = hb * 256 + tid;
      if (i < NNZ){
        int pos = atomicAdd(cursor + edges[i], 1);
        rows[pos] = vertex[i];
      }
    }
    return;
  }

  const int rowIdx = q * 64;
  const int t = (rowIdx >= pbase[1]) + (rowIdx >= pbase[2]) + (rowIdx >= pbase[3]);

  // stage this type's full B (8 ct x 4 ks x 64 lanes, bf16x8 units)
  const bf16x8* Bv = (const bf16x8*)Bfrag;
  bf16x8* shBv = (bf16x8*)shB;
  #pragma unroll
  for (int v = 0; v < 8; ++v){
    int item = v * 256 + tid;                      // 0..2047
    int slab = item >> 6, ln = item & 63;          // slab = ks*8 + ctl
    int ks = slab >> 3, ctl = slab & 7;
    shBv[item] = Bv[((ks * 32 + 8 * t + ctl) * 64) + ln];
  }

  const int w = tid >> 6, lane = tid & 63;
  const int m = lane & 15, qq = lane >> 4;
  const int node = nsorted[rowIdx + w * 16 + m];   // -1 = pad sentinel

  bf16x8 afrag[4];
  #pragma unroll
  for (int ks = 0; ks < 4; ++ks){
    bf16x8 f;
    if (node >= 0){
      const float4* src = (const float4*)(X + (size_t)node * 128 + ks * 32 + qq * 8);
      float4 a = src[0], b = src[1];
      f[0]=(short)f2bf(a.x); f[1]=(short)f2bf(a.y); f[2]=(short)f2bf(a.z); f[3]=(short)f2bf(a.w);
      f[4]=(short)f2bf(b.x); f[5]=(short)f2bf(b.y); f[6]=(short)f2bf(b.z); f[7]=(short)f2bf(b.w);
    } else {
      #pragma unroll
      for (int z = 0; z < 8; ++z) f[z] = 0;
    }
    afrag[ks] = f;
  }

  f32x4 acc[8];
  #pragma unroll
  for (int ct = 0; ct < 8; ++ct){
    acc[ct][0]=0.f; acc[ct][1]=0.f; acc[ct][2]=0.f; acc[ct][3]=0.f;
  }

  __syncthreads();
  #pragma unroll
  for (int ctl = 0; ctl < 8; ++ctl){
    #pragma unroll
    for (int ks = 0; ks < 4; ++ks){
      bf16x8 bf = shBv[(ks * 8 + ctl) * 64 + lane];
      acc[ctl] = __builtin_amdgcn_mfma_f32_16x16x32_bf16(afrag[ks], bf, acc[ctl], 0, 0, 0);
    }
  }

  const int col0 = lane & 15;
  #pragma unroll
  for (int rr = 0; rr < 4; ++rr){
    int row = nsorted[rowIdx + w * 16 + qq * 4 + rr];
    if (row < 0) continue;
    #pragma unroll
    for (int ctl = 0; ctl < 8; ++ctl)
      X0[(size_t)row * 128 + ctl * 16 + col0] = f2bf(acc[ctl][rr]);
  }
}

// ---------------------------------------------------------------------------
// seg_body v1-ILP2 (R8-proven): 2 rows/iter, independent shfl-reduce chains.
// Lane l owns output elems [2l, 2l+1]; head h = l>>3. offs/cnt hold GLOBAL
// positions into the unified rows buffer — pass BASE rows.
// ---------------------------------------------------------------------------
template<int OUT_BF16, int DO_RELU>
__device__ __forceinline__ void seg_body(const unsigned* __restrict__ feat,
    const float* __restrict__ att, const int* __restrict__ rows_sorted,
    const int* __restrict__ offs, const int* __restrict__ cnt,
    const int* __restrict__ stype, void* __restrict__ outbuf,
    int S, int blockId, int tid){
  int wid = tid >> 6, lane = tid & 63;
  int s = blockId * 4 + wid;
  if (s >= S) return;
  int t = stype[s];
  float a0 = att[t * 128 + 2 * lane], a1 = att[t * 128 + 2 * lane + 1];
  int start = offs[s], len = cnt[s];
  float denom = 0.f, acc0 = 0.f, acc1 = 0.f;

  for (int base = 0; base < len; base += 64){
    int m = len - base; if (m > 64) m = 64;
    int idx = 0;
    if (lane < m) idx = rows_sorted[start + base + lane];

    unsigned u0 = 0, u1 = 0, u2 = 0, u3 = 0;
    {
      int r;
      r = __shfl(idx, 0); if (0 < m) u0 = feat[(size_t)r * 64 + lane];
      r = __shfl(idx, 1); if (1 < m) u1 = feat[(size_t)r * 64 + lane];
      r = __shfl(idx, 2); if (2 < m) u2 = feat[(size_t)r * 64 + lane];
      r = __shfl(idx, 3); if (3 < m) u3 = feat[(size_t)r * 64 + lane];
    }
    for (int j = 0; j < m; j += 2){
      unsigned ua = u0, ub = u1;
      u0 = u2; u1 = u3;
      if (j + 4 < m){ int rn = __shfl(idx, j + 4); u2 = feat[(size_t)rn * 64 + lane]; }
      if (j + 5 < m){ int rn = __shfl(idx, j + 5); u3 = feat[(size_t)rn * 64 + lane]; }

      float xa0 = bflo(ua), xa1 = bfhi(ua);
      float xb0 = bflo(ub), xb1 = bfhi(ub);
      float pa = xa0 * a0 + xa1 * a1;
      float pb = xb0 * a0 + xb1 * a1;
      pa += __shfl_xor(pa, 1);  pb += __shfl_xor(pb, 1);
      pa += __shfl_xor(pa, 2);  pb += __shfl_xor(pb, 2);
      pa += __shfl_xor(pa, 4);  pb += __shfl_xor(pb, 4);
      pa = pa > 0.f ? pa : NEG_SLOPE * pa;
      float wa = __expf(pa);
      denom += wa; acc0 += wa * xa0; acc1 += wa * xa1;
      if (j + 1 < m){
        pb = pb > 0.f ? pb : NEG_SLOPE * pb;
        float wb = __expf(pb);
        denom += wb; acc0 += wb * xb0; acc1 += wb * xb1;
      }
    }
  }
  float inv = 1.f / (denom + 1e-16f);
  float v0 = acc0 * inv, v1 = acc1 * inv;
  if (DO_RELU){ v0 = fmaxf(v0, 0.f); v1 = fmaxf(v1, 0.f); }
  if (OUT_BF16){
    unsigned pw = (unsigned)f2bf(v0) | ((unsigned)f2bf(v1) << 16);
    ((unsigned*)outbuf)[(size_t)s * 64 + lane] = pw;
  } else {
    ((float2*)outbuf)[(size_t)s * 64 + lane] = make_float2(v0, v1);
  }
}

// ---------------------------------------------------------------------------
// F_B: fused [place_v | seg1], MODULO-interleaved period 5 (role 0 = place,
// roles 1-4 = seg).  place_v writes rows[NNZ,2NNZ); seg1 reads rows[0,NNZ).
// ---------------------------------------------------------------------------
__global__ __launch_bounds__(256) void k_place_seg1(
    const int* __restrict__ edges, const int* __restrict__ vertex, int NNZ,
    int* __restrict__ cursor, int* __restrict__ rows, int E,
    int nbPlace, int nbSeg,
    const unsigned* __restrict__ X0, const float* __restrict__ att_e,
    const int* __restrict__ offs, const int* __restrict__ cnt,
    const int* __restrict__ etype, void* __restrict__ Xe){
  const int q = (int)blockIdx.x / 5, r = (int)blockIdx.x % 5;
  if (r == 0){
    if (q < nbPlace){
      int i = q * 256 + threadIdx.x;
      if (i < NNZ){
        int pos = atomicAdd(cursor + E + vertex[i], 1);
        rows[pos] = edges[i];
      }
    }
    return;
  }
  int segBlk = q * 4 + (r - 1);
  if (segBlk >= nbSeg) return;
  seg_body<1, 1>(X0, att_e, rows, offs, cnt, etype, Xe, E, segBlk, threadIdx.x);
}

__global__ __launch_bounds__(256) void k_seg2(const unsigned* __restrict__ Xe,
    const float* __restrict__ att_v, const int* __restrict__ rows,
    const int* __restrict__ offs, const int* __restrict__ cnt,
    const int* __restrict__ vtype, float* __restrict__ out, int N){
  seg_body<0, 0>(Xe, att_v, rows, offs, cnt, vtype, out, N,
                 (int)blockIdx.x, threadIdx.x);
}

extern "C" void kernel_launch(void* const* d_in, const int* in_sizes, int n_in,
                              void* d_out, int out_size, void* d_ws, size_t ws_size,
                              hipStream_t stream){
  const float* X      = (const float*)d_in[0];
  const float* W      = (const float*)d_in[1];
  const float* att_e  = (const float*)d_in[2];
  const float* att_v  = (const float*)d_in[3];
  const int*   vertex = (const int*)d_in[4];
  const int*   edges  = (const int*)d_in[5];
  const int*   vtype  = (const int*)d_in[6];
  const int*   etype  = (const int*)d_in[7];
  float* out = (float*)d_out;
  const int N   = in_sizes[0] / 128;
  const int NNZ = in_sizes[4];
  const int E   = in_sizes[7];
  const int S   = E + N;

  const int nbI = (NNZ + 255) / 256;                  // 3125 hist/place blocks
  const int nbHN = (N + 255) / 256;                   // 391 type-hist blocks
  const int nbS = (S + 1023) / 1024;
  const int nbSeg1 = (E + 3) / 4;                     // 12500 seg1 blocks
  const int nbPad = (N + 252 + 63) / 64;              // padded gemm blocks
  const int nsortedCap = nbPad * 64;                  // FULL gemm-grid coverage

  // workspace carve
  char* wp = (char*)d_ws;
  int* cnt    = (int*)wp; wp += (size_t)S * 4;        // [0,E) edge, [E,S) vertex
  int* tcnt   = (int*)wp; wp += 16;                   // node-type counts
  int* tcur   = (int*)wp; wp += 16;                   // node-type cursors
  int* offs   = (int*)wp; wp += (size_t)S * 4;
  int* cursor = (int*)wp; wp += (size_t)S * 4;
  int* bsum   = (int*)wp; wp += 1024;                 // up to 256 block sums
  int* pbase  = (int*)wp; wp += 32;                   // padded bucket bases[5]
  int* rows   = (int*)wp; wp += (size_t)2 * NNZ * 4;  // [0,NNZ) edge-grp, [NNZ,2NNZ) vtx-grp
  int* nsorted= (int*)wp; wp += (size_t)nsortedCap * 4; // type-sorted node ids (pad = -1)
  unsigned short* X0 = (unsigned short*)wp; wp += (size_t)N * 128 * 2;
  unsigned short* Xe = (unsigned short*)wp; wp += (size_t)E * 128 * 2;
  short* Bfrag = (short*)wp; wp += (size_t)65536 * 2;

  hipMemsetAsync(cnt, 0, (size_t)(S + 8) * 4, stream);          // cnt + tcnt + tcur
  hipMemsetAsync(nsorted, 0xFF, (size_t)nsortedCap * 4, stream); // -1 sentinels

  k_histprep<<<nbI + nbHN + 256, 256, 0, stream>>>(edges, vertex, NNZ, cnt, E,
      nbI, vtype, N, tcnt, nbHN, W, Bfrag);

  k_scanA<<<nbS, 256, 0, stream>>>(cnt, S, bsum);
  k_scanB<<<1, 64, 0, stream>>>(bsum, nbS, tcnt, pbase);
  k_scanC<<<nbS + nbHN, 256, 0, stream>>>(cnt, S, bsum, offs, cursor,
      nbS, vtype, N, pbase, tcur, nsorted);

  // F_A interleaved: period 3 (1 gemm : 2 place_e); 2*nbPad >= nbI coverage
  k_gemm_place<<<3 * nbPad, 256, 0, stream>>>(X, Bfrag, nsorted, pbase,
      (unsigned short*)X0, edges, vertex, NNZ, cursor, rows, nbI);

  // F_B interleaved: period 5 (1 place_v : 4 seg1); 5*nbI = nbI + nbSeg1
  k_place_seg1<<<5 * nbI, 256, 0, stream>>>(edges, vertex, NNZ, cursor,
      rows, E, nbI, nbSeg1, (const unsigned*)X0, att_e, offs, cnt, etype, Xe);

  // base rows pointer — offs[E..S) are global positions in [NNZ, 2NNZ)
  k_seg2<<<(N + 3) / 4, 256, 0, stream>>>((const unsigned*)Xe, att_v,
      rows, offs + E, cnt + E, vtype, out, N);
}